// Round 10
// baseline (627.791 us; speedup 1.0000x reference)
//
#include <hip/hip_runtime.h>
#include <math.h>

// Envelope follower: env' = max(ca*env + (1-ca)*|x|, cr*env + (1-cr)*|x|)
// (exact branch-free form since ca < cr). Chunked restart, full-rate warm-up
// W=24576 (proven absmax 0.0078 = bf16 compare floor).
// R10 = R9 row-split (4 waves/chunk, 16 rows each, ring-8 depth-4 DMA,
//       counted vmcnt(16)) + R8 lockstep warm-up (groups of G=4 chunks all
//       start at base-W so their reads coincide -> one L2 fill serves 4
//       blocks; R8 measured 87% hit) + XCD co-location (group members at
//       b === g (mod 8) land on one XCD under the runtime's round-robin).
//     R9 was queueing-equilibrium bound at 2.6 TB/s service with 47% HBM
//     miss; lockstep turns the misses into XCD-local L2 hits so T_iter
//     should collapse toward the ~640-1000 cyc/tile chain floor.

namespace {

constexpr int NL    = 480000;
constexpr int TS    = 64;               // samples per tile
constexpr int CHUNK = 1920;             // payload per chunk
constexpr int NCH   = NL / CHUNK;       // 250 chunks
constexpr int G     = 4;                // chunks per lockstep group
constexpr int GSPAN = G * CHUNK;        // 7680
constexpr int NGRP  = (NCH + G - 1) / G;   // 63 (last group has 2 members)
constexpr int WARM  = 24576;            // warm-up samples
constexpr int RING  = 8;                // ring slots per wave
constexpr int DEPTH = 4;                // tiles prefetched ahead

typedef const __attribute__((address_space(1))) void* gas_t;
typedef __attribute__((address_space(3))) void* las_t;
typedef float v2f __attribute__((ext_vector_type(2)));

__device__ __forceinline__ void gl_lds16(const void* gp, void* lp) {
    __builtin_amdgcn_global_load_lds((gas_t)gp, (las_t)lp, 16, 0, 0);
}

__global__ __launch_bounds__(256, 1)
void envfollow_kernel(const float* __restrict__ x,
                      const float* __restrict__ p_ra,
                      const float* __restrict__ p_rr,
                      const int*   __restrict__ p_sr,
                      float* __restrict__ out)
{
    // ---- block decode: group g member j at b = (g%8) + 8*(4*(g/8)+j) ----
    // => xcd = b%8, slot = b/8, j = slot%4, g = 8*(slot/4) + xcd
    const int b    = blockIdx.x;            // 0..255
    const int xcd  = b & 7;
    const int slot = b >> 3;                // 0..31
    const int j    = slot & 3;              // member 0..3
    const int g    = 8 * (slot >> 2) + xcd; // group 0..63
    if (g >= NGRP) return;
    const int c = G * g + j;                // chunk id
    if (c >= NCH) return;

    // per-wave structures; waves never share data -> no barriers anywhere
    __shared__ float4 ring[4][RING][256];   // [wave][slot][4KB tile]
    __shared__ float4 sO[4][16 * 17];       // [wave][row][16+pad] output stage

    const int tid  = threadIdx.x;
    const int w    = tid >> 6;              // wave 0..3
    const int ln   = tid & 63;              // lane
    const int lj   = ln >> 4;               // 0..3 (row-within-instr / swz key)
    const int lk   = ln & 15;               // 0..15 (col quad)
    const int l    = ln;                    // chain lane (< 16 active)

    const int base      = g * GSPAN;        // group base (member-0 payload)
    const int pay_begin = c * CHUNK;
    const int pay_end   = pay_begin + CHUNK;
    int t0 = base - WARM; if (t0 < 0) t0 = 0;   // SHARED start, tile-aligned

    // coefficients (match reference fp32 math; sigmoid(0)=0.5 exact)
    const float sr   = (float)p_sr[0];
    const float siga = 1.0f / (1.0f + expf(-p_ra[0]));
    const float sigr = 1.0f / (1.0f + expf(-p_rr[0]));
    const float ca  = expf(-1000.0f / ((0.1f  + 49.9f  * siga) * sr));
    const float cr  = expf(-1000.0f / ((10.0f + 490.0f * sigr) * sr));
    const v2f cf = {ca, cr};
    const v2f om = {1.0f - ca, 1.0f - cr};

    // rows owned by this wave: 16w .. 16w+15
    const int rbase = 16 * w;

    // STAGE one 4KB tile (16 rows x 64 samples) at column T into ring[w][S].
    // instr g2 covers rows rbase+4*g2+lj; source col swizzled (lk ^ lj) so
    // chain ds_read_b128 are 4-way instead of 16-way bank conflicted.
#define STAGE(T, S) do { _Pragma("unroll") \
    for (int g2 = 0; g2 < 4; ++g2) { \
        const int row_ = rbase + 4*g2 + lj; \
        gl_lds16(x + (size_t)row_ * NL + (T) + 4*(lk ^ lj), \
                 (char*)(&ring[w][S][0]) + g2 * 1024); \
    } } while (0)

#define STEP(XV, OV) do { \
        const float la_ = fabsf(XV); \
        const v2f   of_ = om * (v2f){la_, la_}; \
        const v2f   f_  = __builtin_elementwise_fma(cf, (v2f){env, env}, of_); \
        env = fmaxf(f_[0], f_[1]); \
        (OV) = env; \
    } while (0)

    // store wave's 16x64 payload tile: instr g2 covers rows rbase+4*g2+lj
#define FLUSH(TB) do { _Pragma("unroll") \
    for (int g2 = 0; g2 < 4; ++g2) { \
        const float4 og = sO[w][(4*g2 + lj) * 17 + lk]; \
        *reinterpret_cast<float4*>( \
            out + (size_t)(rbase + 4*g2 + lj) * NL + (TB) + 4*lk) = og; \
    } } while (0)

    float env = 0.0f;
    const int NT = (pay_end - t0) / TS;     // up to 504 tiles (member 3)

    // ---- prologue: stage tiles 0..3 into slots 0..3 ----
    STAGE(t0,          0);
    STAGE(t0 +   TS,   1);
    STAGE(t0 + 2*TS,   2);
    STAGE(t0 + 3*TS,   3);

    for (int i = 0; i < NT; ++i) {
        const int tb = t0 + i * TS;

        // issue tile i+DEPTH (clamped re-stage of the last tile at the end;
        // it lands in an already-consumed slot -> safe)
        int it = i + DEPTH; if (it > NT - 1) it = NT - 1;
        STAGE(t0 + it * TS, (i + DEPTH) & (RING - 1));

        // wait until <=16 VMEM outstanding => tile i resident;
        // 4 tiles (16 loads) stay in flight (never vmcnt(0) in the loop)
        asm volatile("s_waitcnt vmcnt(16)" ::: "memory");

        if (l < 16) {
            // tile -> registers (16 ds_read_b128, swizzled slots)
            float4 v[16];
            const float4* slab = &ring[w][i & (RING - 1)][0];
#pragma unroll
            for (int k = 0; k < 16; ++k)
                v[k] = slab[(l >> 2) * 64 + (l & 3) * 16 + (k ^ (l & 3))];

            // serial 64-step chain, pure-register operands; outputs -> sO
#pragma unroll
            for (int k = 0; k < 16; ++k) {
                float4 o;
                STEP(v[k].x, o.x);
                STEP(v[k].y, o.y);
                STEP(v[k].z, o.z);
                STEP(v[k].w, o.w);
                sO[w][l * 17 + k] = o;
            }
        }

        // flush this payload tile (same wave wrote sO; in-order LDS pipe ->
        // compiler's lgkmcnt ordering suffices)
        if (tb >= pay_begin) FLUSH(tb);
    }

#undef STAGE
#undef STEP
#undef FLUSH
}

} // namespace

extern "C" void kernel_launch(void* const* d_in, const int* in_sizes, int n_in,
                              void* d_out, int out_size, void* d_ws, size_t ws_size,
                              hipStream_t stream)
{
    const float* x   = (const float*)d_in[0];
    const float* ra  = (const float*)d_in[1];
    const float* rr  = (const float*)d_in[2];
    const int*   srp = (const int*)d_in[3];
    float* out = (float*)d_out;

    envfollow_kernel<<<256, 256, 0, stream>>>(x, ra, rr, srp, out);
}

// Round 11
// 524.960 us; speedup vs baseline: 1.1959x; 1.1959x over previous
//
#include <hip/hip_runtime.h>
#include <math.h>

// Envelope follower: env' = max(ca*env + (1-ca)*|x|, cr*env + (1-cr)*|x|)
// (exact branch-free form since ca < cr). Chunked restart, full-rate warm-up
// W=24576 (proven absmax 0.0078 = bf16 compare floor).
// R11: cross-round law: demand service ~4-4.5 B/cyc per resident BLOCK
//      (R4: 2 blocks/CU -> 7.8 B/cyc/CU; R1/R7/R8/R9/R10: 1 block/CU -> ~4.5
//      regardless of cache hit rate, waves/block, prefetch depth). R9/R10's
//      145KB-LDS blocks capped each CU at one block. So: repackage R9 as
//      1000 SINGLE-WAVE blocks (chunk x 16-row group), 36.6KB LDS each ->
//      4 blocks/CU. Same tiles, same DMA structure, same counted vmcnt(16),
//      same numerics; block granularity is the only variable.
//      Also: source permute key row&7 (was row&3) -> chain ds_read_b128
//      2-way banked (free) instead of 4-way.

namespace {

constexpr int NL    = 480000;
constexpr int TS    = 64;               // samples per tile
constexpr int CHUNK = 1920;             // payload per chunk
constexpr int NCH   = NL / CHUNK;       // 250 chunks
constexpr int WARM  = 24576;            // warm-up samples
constexpr int RING  = 8;                // ring slots (4KB each)
constexpr int DEPTH = 4;                // tiles prefetched ahead

typedef const __attribute__((address_space(1))) void* gas_t;
typedef __attribute__((address_space(3))) void* las_t;
typedef float v2f __attribute__((ext_vector_type(2)));

__device__ __forceinline__ void gl_lds16(const void* gp, void* lp) {
    __builtin_amdgcn_global_load_lds((gas_t)gp, (las_t)lp, 16, 0, 0);
}

__global__ __launch_bounds__(64, 1)
void envfollow_kernel(const float* __restrict__ x,
                      const float* __restrict__ p_ra,
                      const float* __restrict__ p_rr,
                      const int*   __restrict__ p_sr,
                      float* __restrict__ out)
{
    // one wave per block; 36.6KB LDS -> 4 blocks/CU
    __shared__ float4 ring[RING][256];      // [slot][4KB tile: 16 rows x 64]
    __shared__ float4 sO[16 * 17];          // [row][16+pad] output stage

    const int b  = blockIdx.x;              // 0..999
    const int c  = b >> 2;                  // chunk 0..249
    const int rg = b & 3;                   // row group 0..3

    const int ln = threadIdx.x;             // lane
    const int lj = ln >> 4;                 // 0..3 (row-within-instr)
    const int lk = ln & 15;                 // 0..15 (col quad)
    const int l  = ln;                      // chain lane (< 16 active)

    const int rbase = 16 * rg;              // rows rbase..rbase+15
    const int pay_begin = c * CHUNK;
    const int pay_end   = pay_begin + CHUNK;
    int t0 = pay_begin - WARM; if (t0 < 0) t0 = 0;   // tile-aligned

    // coefficients (match reference fp32 math; sigmoid(0)=0.5 exact)
    const float sr   = (float)p_sr[0];
    const float siga = 1.0f / (1.0f + expf(-p_ra[0]));
    const float sigr = 1.0f / (1.0f + expf(-p_rr[0]));
    const float ca  = expf(-1000.0f / ((0.1f  + 49.9f  * siga) * sr));
    const float cr  = expf(-1000.0f / ((10.0f + 490.0f * sigr) * sr));
    const v2f cf = {ca, cr};
    const v2f om = {1.0f - ca, 1.0f - cr};

    // STAGE one 4KB tile (16 rows x 64 samples) at column T into ring[S].
    // instr g2 covers rows rbase+4*g2+lj (256B contiguous per row, permuted
    // within); source col quad = lk ^ (row&7) so the chain's ds_read_b128
    // land 2 lanes per bank-quad (free).
#define STAGE(T, S) do { _Pragma("unroll") \
    for (int g2 = 0; g2 < 4; ++g2) { \
        const int row_ = rbase + 4*g2 + lj; \
        const int cq_  = lk ^ lj ^ ((g2 & 1) << 2); \
        gl_lds16(x + (size_t)row_ * NL + (T) + 4*cq_, \
                 (char*)(&ring[S][0]) + g2 * 1024); \
    } } while (0)

#define STEP(XV, OV) do { \
        const float la_ = fabsf(XV); \
        const v2f   of_ = om * (v2f){la_, la_}; \
        const v2f   f_  = __builtin_elementwise_fma(cf, (v2f){env, env}, of_); \
        env = fmaxf(f_[0], f_[1]); \
        (OV) = env; \
    } while (0)

    // store this block's 16x64 payload tile: instr g2 covers rows rbase+4g2+lj
#define FLUSH(TB) do { _Pragma("unroll") \
    for (int g2 = 0; g2 < 4; ++g2) { \
        const float4 og = sO[(4*g2 + lj) * 17 + lk]; \
        *reinterpret_cast<float4*>( \
            out + (size_t)(rbase + 4*g2 + lj) * NL + (TB) + 4*lk) = og; \
    } } while (0)

    float env = 0.0f;
    const int NT = (pay_end - t0) / TS;     // 30 (early chunks) .. 414

    // ---- prologue: stage tiles 0..3 into slots 0..3 (16 loads in flight) ----
    STAGE(t0,          0);
    STAGE(t0 +   TS,   1);
    STAGE(t0 + 2*TS,   2);
    STAGE(t0 + 3*TS,   3);

    for (int i = 0; i < NT; ++i) {
        const int tb = t0 + i * TS;

        // issue tile i+DEPTH (clamped re-stage of the last tile at the end;
        // lands in an already-consumed slot -> safe)
        int it = i + DEPTH; if (it > NT - 1) it = NT - 1;
        STAGE(t0 + it * TS, (i + DEPTH) & (RING - 1));

        // wait until <=16 VMEM outstanding => tile i resident;
        // 4 tiles (16 loads) stay in flight (never vmcnt(0) in the loop)
        asm volatile("s_waitcnt vmcnt(16)" ::: "memory");

        if (l < 16) {
            // tile -> registers (16 ds_read_b128, 2-way banked)
            float4 v[16];
            const float4* slab = &ring[i & (RING - 1)][0];
#pragma unroll
            for (int k = 0; k < 16; ++k)
                v[k] = slab[(l >> 2) * 64 + (l & 3) * 16 + (k ^ (l & 7))];

            // serial 64-step chain, pure-register operands; outputs -> sO
#pragma unroll
            for (int k = 0; k < 16; ++k) {
                float4 o;
                STEP(v[k].x, o.x);
                STEP(v[k].y, o.y);
                STEP(v[k].z, o.z);
                STEP(v[k].w, o.w);
                sO[l * 17 + k] = o;
            }
        }

        // flush this payload tile (same wave wrote sO; in-order LDS pipe ->
        // compiler's lgkmcnt ordering suffices)
        if (tb >= pay_begin) FLUSH(tb);
    }

#undef STAGE
#undef STEP
#undef FLUSH
}

} // namespace

extern "C" void kernel_launch(void* const* d_in, const int* in_sizes, int n_in,
                              void* d_out, int out_size, void* d_ws, size_t ws_size,
                              hipStream_t stream)
{
    const float* x   = (const float*)d_in[0];
    const float* ra  = (const float*)d_in[1];
    const float* rr  = (const float*)d_in[2];
    const int*   srp = (const int*)d_in[3];
    float* out = (float*)d_out;

    envfollow_kernel<<<4 * NCH, 64, 0, stream>>>(x, ra, rr, srp, out);
}

// Round 15
// 441.135 us; speedup vs baseline: 1.4231x; 1.1900x over previous
//
#include <hip/hip_runtime.h>
#include <math.h>

// Envelope follower: env' = max(ca*env + (1-ca)*|x|, cr*env + (1-cr)*|x|)
// (exact branch-free form since ca < cr). Chunked restart, full-rate warm-up
// W=24576 (proven absmax 0.0078 = bf16 compare floor).
// R15: amortization experiment as a MINIMAL delta on the proven R11 kernel
//      (R12-R14 rebuilt geometry+staging+chain at once and broke correctness
//      twice). R11 verbatim: 1000 single-wave blocks (chunk x 16-row group),
//      4KB tiles, source permute, swizzled slab reads, sO[16][17], FLUSH,
//      packed STEP, W=24576, CHUNK=1920. ONLY change: tiles consumed in
//      GROUPS OF 4 with ONE vmcnt(16) per group (retires current group +
//      stores, keeps next group's 16 loads in flight) -> 104 wait-boundaries
//      per wave instead of 414. Ring = 8 slots (32KB); consuming half {0-3}
//      and staging half {4-7} alternate. Tail: clamp-dup staging (proven) +
//      uniform if(t<NT) consumption guard.
//      Discriminator: per-boundary fixed-cost law -> ~175us/wave; per-byte
//      bandwidth law -> unchanged ~640us.

namespace {

constexpr int NL    = 480000;
constexpr int TS    = 64;               // samples per tile
constexpr int CHUNK = 1920;             // payload per chunk
constexpr int NCH   = NL / CHUNK;       // 250 chunks
constexpr int WARM  = 24576;            // warm-up samples
constexpr int RING  = 8;                // ring slots (4KB each)

typedef const __attribute__((address_space(1))) void* gas_t;
typedef __attribute__((address_space(3))) void* las_t;
typedef float v2f __attribute__((ext_vector_type(2)));

__device__ __forceinline__ void gl_lds16(const void* gp, void* lp) {
    __builtin_amdgcn_global_load_lds((gas_t)gp, (las_t)lp, 16, 0, 0);
}

__global__ __launch_bounds__(64, 1)
void envfollow_kernel(const float* __restrict__ x,
                      const float* __restrict__ p_ra,
                      const float* __restrict__ p_rr,
                      const int*   __restrict__ p_sr,
                      float* __restrict__ out)
{
    __shared__ float4 ring[RING][256];      // [slot][4KB tile: 16 rows x 64]
    __shared__ float4 sO[16 * 17];          // [row][16+pad] output stage

    const int b  = blockIdx.x;              // 0..999
    const int c  = b >> 2;                  // chunk 0..249
    const int rg = b & 3;                   // row group 0..3

    const int ln = threadIdx.x;             // lane
    const int lj = ln >> 4;                 // 0..3 (row-within-instr)
    const int lk = ln & 15;                 // 0..15 (col quad)
    const int l  = ln;                      // chain lane (< 16 active)

    const int rbase = 16 * rg;              // rows rbase..rbase+15
    const int pay_begin = c * CHUNK;
    const int pay_end   = pay_begin + CHUNK;
    int t0 = pay_begin - WARM; if (t0 < 0) t0 = 0;   // tile-aligned

    // coefficients (match reference fp32 math; sigmoid(0)=0.5 exact)
    const float sr   = (float)p_sr[0];
    const float siga = 1.0f / (1.0f + expf(-p_ra[0]));
    const float sigr = 1.0f / (1.0f + expf(-p_rr[0]));
    const float ca  = expf(-1000.0f / ((0.1f  + 49.9f  * siga) * sr));
    const float cr  = expf(-1000.0f / ((10.0f + 490.0f * sigr) * sr));
    const v2f cf = {ca, cr};
    const v2f om = {1.0f - ca, 1.0f - cr};

    // STAGE one 4KB tile (16 rows x 64 samples) at column T into ring[S].
    // instr g2 covers rows rbase+4*g2+lj; source col quad = lk ^ (row&7)
    // so the chain's ds_read_b128 are 2-way banked (free).   [R11 verbatim]
#define STAGE(T, S) do { _Pragma("unroll") \
    for (int g2 = 0; g2 < 4; ++g2) { \
        const int row_ = rbase + 4*g2 + lj; \
        const int cq_  = lk ^ lj ^ ((g2 & 1) << 2); \
        gl_lds16(x + (size_t)row_ * NL + (T) + 4*cq_, \
                 (char*)(&ring[S][0]) + g2 * 1024); \
    } } while (0)

#define STEP(XV, OV) do { \
        const float la_ = fabsf(XV); \
        const v2f   of_ = om * (v2f){la_, la_}; \
        const v2f   f_  = __builtin_elementwise_fma(cf, (v2f){env, env}, of_); \
        env = fmaxf(f_[0], f_[1]); \
        (OV) = env; \
    } while (0)

    // store this block's 16x64 payload tile      [R11 verbatim]
#define FLUSH(TB) do { _Pragma("unroll") \
    for (int g2 = 0; g2 < 4; ++g2) { \
        const float4 og = sO[(4*g2 + lj) * 17 + lk]; \
        *reinterpret_cast<float4*>( \
            out + (size_t)(rbase + 4*g2 + lj) * NL + (TB) + 4*lk) = og; \
    } } while (0)

    float env = 0.0f;
    const int NT = (pay_end - t0) / TS;     // 30 (early chunks) .. 414
    const int NG = (NT + 3) >> 2;           // groups of 4 tiles

    // ---- prologue: stage group 0 = tiles 0..3 (NT >= 30 always) ----
    STAGE(t0,          0);
    STAGE(t0 +   TS,   1);
    STAGE(t0 + 2*TS,   2);
    STAGE(t0 + 3*TS,   3);

    for (int G = 0; G < NG; ++G) {
        // stage group G+1 (tiles 4G+4..4G+7; clamp-dup at the tail: the
        // duplicate writes carry identical data into the same slot -> safe)
#pragma unroll
        for (int s = 0; s < 4; ++s) {
            int jt = 4*G + 4 + s; if (jt > NT - 1) jt = NT - 1;
            STAGE(t0 + jt * TS, jt & (RING - 1));
        }

        // ONE counted wait per group: leaves only the 16 youngest VMEM ops
        // (= group G+1's prefetch) outstanding; group G's 16 loads and all
        // older stores are retired. Never vmcnt(0) in the loop.
        asm volatile("s_waitcnt vmcnt(16)" ::: "memory");

        // consume the 4 resident tiles of group G
#pragma unroll
        for (int s = 0; s < 4; ++s) {
            const int t = 4*G + s;
            if (t < NT) {                   // uniform across the wave
                const int tb = t0 + t * TS;

                if (l < 16) {
                    // tile -> registers (16 ds_read_b128, 2-way banked)
                    float4 v[16];
                    const float4* slab = &ring[t & (RING - 1)][0];
#pragma unroll
                    for (int k = 0; k < 16; ++k)
                        v[k] = slab[(l >> 2) * 64 + (l & 3) * 16 + (k ^ (l & 7))];

                    // serial 64-step chain; outputs -> sO
#pragma unroll
                    for (int k = 0; k < 16; ++k) {
                        float4 o;
                        STEP(v[k].x, o.x);
                        STEP(v[k].y, o.y);
                        STEP(v[k].z, o.z);
                        STEP(v[k].w, o.w);
                        sO[l * 17 + k] = o;
                    }
                }

                // flush payload tile (same wave wrote sO; in-order LDS pipe)
                if (tb >= pay_begin) FLUSH(tb);
            }
        }
    }

#undef STAGE
#undef STEP
#undef FLUSH
}

} // namespace

extern "C" void kernel_launch(void* const* d_in, const int* in_sizes, int n_in,
                              void* d_out, int out_size, void* d_ws, size_t ws_size,
                              hipStream_t stream)
{
    const float* x   = (const float*)d_in[0];
    const float* ra  = (const float*)d_in[1];
    const float* rr  = (const float*)d_in[2];
    const int*   srp = (const int*)d_in[3];
    float* out = (float*)d_out;

    envfollow_kernel<<<4 * NCH, 64, 0, stream>>>(x, ra, rr, srp, out);
}